// Round 6
// baseline (295.775 us; speedup 1.0000x reference)
//
#include <hip/hip_runtime.h>
#include <math.h>

#define BB 8
#define HH 448
#define WW 1024
#define HWSZ (HH*WW)
#define NPIX (BB*HH*WW)
#define CR 3
#define TX 64
#define TY 16
#define HX (TX+2*CR)   // 70
#define HXP 72         // padded LDS row stride
#define HY (TY+2*CR)   // 22
#define NBX 16
#define NBY 28
#define NB  (NBX*NBY*BB)   // 3584 fused blocks

__device__ __forceinline__ float pen45(float dd) {   // dd = d*d + eps, dd > 0
    return __expf(0.45f * __logf(dd));
}

__device__ __forceinline__ float gray3(float r, float g, float b) {
    return (0.299f * r + 0.587f * g + 0.114f * b) * 255.0f;
}

// ws layout: part_cen[NB] | part_sx[NB] | part_sy[NB] | part_epe[NB]

__global__ __launch_bounds__(256) void k_fused(
    const float* __restrict__ flow, const float* __restrict__ target,
    const float* __restrict__ img1, const float* __restrict__ img2,
    float* __restrict__ part)
{
    __shared__ float t1s[HY][HXP];
    __shared__ float t2s[HY][HXP];
    __shared__ float fus[HY][HXP];
    __shared__ float fvs[HY][HXP];

    const int b  = blockIdx.z;
    const int x0 = blockIdx.x * TX;    // centers x0..x0+63 (covers 0..1023 exactly)
    const int y0 = blockIdx.y * TY;    // centers y0..y0+15 (covers 0..447 exactly)
    const int tid = threadIdx.x;

    const float* i1r = img1 + (size_t)b * 3 * HWSZ;
    const float* i1g = i1r + HWSZ;
    const float* i1b = i1r + 2 * HWSZ;
    const float* i2r = img2 + (size_t)b * 3 * HWSZ;
    const float* i2g = i2r + HWSZ;
    const float* i2b = i2r + 2 * HWSZ;
    const float* fu  = flow + (size_t)b * 2 * HWSZ;
    const float* fv  = fu + HWSZ;
    const float* tu  = target + (size_t)b * 2 * HWSZ;
    const float* tv  = tu + HWSZ;

    // ---- stage halo tile: gray1, warped-gray2 (direct from img2 channels), flow ----
    for (int i = tid; i < HY * HX; i += 256) {
        int ly = i / HX, lx = i - ly * HX;
        int gx = x0 - CR + lx; gx = gx < 0 ? 0 : (gx > WW - 1 ? WW - 1 : gx);
        int gy = y0 - CR + ly; gy = gy < 0 ? 0 : (gy > HH - 1 ? HH - 1 : gy);
        int gidx = gy * WW + gx;
        t1s[ly][lx] = gray3(i1r[gidx], i1g[gidx], i1b[gidx]);
        float u = fu[gidx], v = fv[gidx];
        fus[ly][lx] = u; fvs[ly][lx] = v;
        float xx = (float)gx + u, yy = (float)gy + v;
        float fx = floorf(xx), fy = floorf(yy);
        float wx = xx - fx, wy = yy - fy;
        int xi0 = (int)fx; xi0 = xi0 < 0 ? 0 : (xi0 > WW - 1 ? WW - 1 : xi0);
        int xi1 = xi0 + 1 > WW - 1 ? WW - 1 : xi0 + 1;
        int yi0 = (int)fy; yi0 = yi0 < 0 ? 0 : (yi0 > HH - 1 ? HH - 1 : yi0);
        int yi1 = yi0 + 1 > HH - 1 ? HH - 1 : yi0 + 1;
        int i00 = yi0 * WW + xi0, i01 = yi0 * WW + xi1;
        int i10 = yi1 * WW + xi0, i11 = yi1 * WW + xi1;
        float g00 = gray3(i2r[i00], i2g[i00], i2b[i00]);
        float g01 = gray3(i2r[i01], i2g[i01], i2b[i01]);
        float g10 = gray3(i2r[i10], i2g[i10], i2b[i10]);
        float g11 = gray3(i2r[i11], i2g[i11], i2b[i11]);
        t2s[ly][lx] = g00 * ((1.0f - wx) * (1.0f - wy)) + g01 * (wx * (1.0f - wy))
                    + g10 * ((1.0f - wx) * wy) + g11 * (wx * wy);
    }
    __syncthreads();

    // ---- census: each thread owns a 1x4 strip of centers ----
    const int txg = tid & 15;
    const int ty  = tid >> 4;          // 0..15
    const int lxb = txg * 4;           // halo col base; centers at lxb+CR+k
    const int rowc = ty + CR;

    float dist[4] = {0.f, 0.f, 0.f, 0.f};
    float c1[4], c2[4];

#define LOADROW(ROW, V1, V2)                                            \
    float V1[12], V2[12];                                               \
    {                                                                   \
        float4 _a0 = *(const float4*)&t1s[ROW][lxb];                    \
        float4 _a1 = *(const float4*)&t1s[ROW][lxb + 4];                \
        float4 _a2 = *(const float4*)&t1s[ROW][lxb + 8];                \
        float4 _b0 = *(const float4*)&t2s[ROW][lxb];                    \
        float4 _b1 = *(const float4*)&t2s[ROW][lxb + 4];                \
        float4 _b2 = *(const float4*)&t2s[ROW][lxb + 8];                \
        V1[0]=_a0.x; V1[1]=_a0.y; V1[2]=_a0.z; V1[3]=_a0.w;             \
        V1[4]=_a1.x; V1[5]=_a1.y; V1[6]=_a1.z; V1[7]=_a1.w;             \
        V1[8]=_a2.x; V1[9]=_a2.y; V1[10]=_a2.z; V1[11]=_a2.w;           \
        V2[0]=_b0.x; V2[1]=_b0.y; V2[2]=_b0.z; V2[3]=_b0.w;             \
        V2[4]=_b1.x; V2[5]=_b1.y; V2[6]=_b1.z; V2[7]=_b1.w;             \
        V2[8]=_b2.x; V2[9]=_b2.y; V2[10]=_b2.z; V2[11]=_b2.w;           \
    }

#define PAIR(V1, V2, K, DX)                                              \
    {                                                                    \
        float _d1 = V1[3 + (K) + (DX)] - c1[K];                          \
        float _d2 = V2[3 + (K) + (DX)] - c2[K];                          \
        float _u1 = _d1 * __builtin_amdgcn_rsqf(fmaf(_d1, _d1, 0.81f));  \
        float _u2 = _d2 * __builtin_amdgcn_rsqf(fmaf(_d2, _d2, 0.81f));  \
        float _dd = _u1 - _u2;                                           \
        float _s = _dd * _dd;                                            \
        dist[K] = fmaf(_s, __builtin_amdgcn_rcpf(0.1f + _s), dist[K]);   \
    }

    {
        LOADROW(rowc, v1, v2)
        #pragma unroll
        for (int k = 0; k < 4; k++) { c1[k] = v1[3 + k]; c2[k] = v2[3 + k]; }
        #pragma unroll
        for (int k = 0; k < 4; k++) {
            #pragma unroll
            for (int dx = -CR; dx <= CR; dx++) {
                if (dx == 0) continue;
                PAIR(v1, v2, k, dx)
            }
        }
    }
    #pragma unroll
    for (int dyi = 0; dyi < 6; dyi++) {
        const int dy = (dyi < 3) ? (dyi - 3) : (dyi - 2);   // -3,-2,-1,1,2,3
        const int row = rowc + dy;
        LOADROW(row, v1, v2)
        #pragma unroll
        for (int k = 0; k < 4; k++) {
            #pragma unroll
            for (int dx = -CR; dx <= CR; dx++) {
                PAIR(v1, v2, k, dx)
            }
        }
    }
#undef LOADROW
#undef PAIR

    const int cy = y0 + ty;
    const int cxb = x0 + lxb;

    // census sum: inner-region validity + flow border mask (from staged flow)
    float s_cen = 0.0f;
    #pragma unroll
    for (int k = 0; k < 4; k++) {
        const int cx = cxb + k;
        const bool validc = (cx >= CR) && (cx <= WW - 1 - CR) && (cy >= CR) && (cy <= HH - 1 - CR);
        float u = fus[rowc][lxb + CR + k], v = fvs[rowc][lxb + CR + k];
        float xx = (float)cx + u, yy = (float)cy + v;
        const bool inside = (xx >= 0.0f) && (xx <= (float)(WW - 1)) &&
                            (yy >= 0.0f) && (yy <= (float)(HH - 1));
        if (validc && inside) s_cen += pen45(fmaf(dist[k], dist[k], 1e-6f));
    }

    // ---- smoothness + EPE for the same 4-center strip ----
    const int gidx  = cy * WW + cxb;
    const int xnext = (cxb + 4 > WW - 1) ? (WW - 1) : (cxb + 4);   // clamped (masked when OOB)
    const int gidxn = cy * WW + xnext;
    const int ydn   = (cy + 1 > HH - 1) ? (HH - 1) : (cy + 1);
    const int gidxd = ydn * WW + cxb;

    float4 r4 = *(const float4*)(i1r + gidx);
    float4 g4 = *(const float4*)(i1g + gidx);
    float4 b4 = *(const float4*)(i1b + gidx);
    float rn = i1r[gidxn], gn = i1g[gidxn], bn = i1b[gidxn];
    float4 u4 = *(const float4*)(fu + gidx);
    float4 v4 = *(const float4*)(fv + gidx);
    float un = fu[gidxn], vn = fv[gidxn];
    float4 tu4 = *(const float4*)(tu + gidx);
    float4 tv4 = *(const float4*)(tv + gidx);

    float R[5] = {r4.x, r4.y, r4.z, r4.w, rn};
    float G[5] = {g4.x, g4.y, g4.z, g4.w, gn};
    float Bc[5] = {b4.x, b4.y, b4.z, b4.w, bn};
    float U[5] = {u4.x, u4.y, u4.z, u4.w, un};
    float V[5] = {v4.x, v4.y, v4.z, v4.w, vn};
    float TU[4] = {tu4.x, tu4.y, tu4.z, tu4.w};
    float TV[4] = {tv4.x, tv4.y, tv4.z, tv4.w};

    float s_ep = 0.0f, s_sx = 0.0f, s_sy = 0.0f;
    #pragma unroll
    for (int k = 0; k < 4; k++) {
        float du = U[k] - TU[k], dv = V[k] - TV[k];
        s_ep += sqrtf(du * du + dv * dv);
        if (cxb + k < WW - 1) {
            float ad = fabsf(R[k] - R[k+1]) + fabsf(G[k] - G[k+1]) + fabsf(Bc[k] - Bc[k+1]);
            float wx = __expf(-(4.0f / 3.0f) * ad);
            float d0 = U[k] - U[k+1], d1 = V[k] - V[k+1];
            s_sx += wx * (pen45(fmaf(d0, d0, 1e-6f)) + pen45(fmaf(d1, d1, 1e-6f)));
        }
    }

    if (cy < HH - 1) {
        float4 rd = *(const float4*)(i1r + gidxd);
        float4 gd = *(const float4*)(i1g + gidxd);
        float4 bd = *(const float4*)(i1b + gidxd);
        float4 ud = *(const float4*)(fu + gidxd);
        float4 vd = *(const float4*)(fv + gidxd);
        float RD[4] = {rd.x, rd.y, rd.z, rd.w};
        float GD[4] = {gd.x, gd.y, gd.z, gd.w};
        float BD[4] = {bd.x, bd.y, bd.z, bd.w};
        float UD[4] = {ud.x, ud.y, ud.z, ud.w};
        float VD[4] = {vd.x, vd.y, vd.z, vd.w};
        #pragma unroll
        for (int k = 0; k < 4; k++) {
            float ad = fabsf(R[k] - RD[k]) + fabsf(G[k] - GD[k]) + fabsf(Bc[k] - BD[k]);
            float wy = __expf(-(4.0f / 3.0f) * ad);
            float d0 = U[k] - UD[k], d1 = V[k] - VD[k];
            s_sy += wy * (pen45(fmaf(d0, d0, 1e-6f)) + pen45(fmaf(d1, d1, 1e-6f)));
        }
    }

    // ---- block reduction of 4 scalars ----
    #pragma unroll
    for (int off = 32; off; off >>= 1) {
        s_cen += __shfl_down(s_cen, off);
        s_sx  += __shfl_down(s_sx, off);
        s_sy  += __shfl_down(s_sy, off);
        s_ep  += __shfl_down(s_ep, off);
    }
    __shared__ float red[4][4];
    const int lane = tid & 63, wid = tid >> 6;
    if (lane == 0) { red[0][wid] = s_cen; red[1][wid] = s_sx; red[2][wid] = s_sy; red[3][wid] = s_ep; }
    __syncthreads();
    if (tid == 0) {
        const int bid = (b * NBY + blockIdx.y) * NBX + blockIdx.x;
        part[bid]           = red[0][0] + red[0][1] + red[0][2] + red[0][3];
        part[NB + bid]      = red[1][0] + red[1][1] + red[1][2] + red[1][3];
        part[2 * NB + bid]  = red[2][0] + red[2][1] + red[2][2] + red[2][3];
        part[3 * NB + bid]  = red[3][0] + red[3][1] + red[3][2] + red[3][3];
    }
}

__global__ __launch_bounds__(256) void k_final(
    const float* __restrict__ part, float* __restrict__ out)
{
    const int tid = threadIdx.x;
    float cn = 0.f, sx = 0.f, sy = 0.f, ep = 0.f;
    for (int i = tid; i < NB; i += 256) {
        cn += part[i];
        sx += part[NB + i];
        sy += part[2 * NB + i];
        ep += part[3 * NB + i];
    }
    #pragma unroll
    for (int off = 32; off; off >>= 1) {
        cn += __shfl_down(cn, off); sx += __shfl_down(sx, off);
        sy += __shfl_down(sy, off); ep += __shfl_down(ep, off);
    }
    __shared__ float r[4][4];
    const int lane = tid & 63, wid = tid >> 6;
    if (lane == 0) { r[0][wid] = cn; r[1][wid] = sx; r[2][wid] = sy; r[3][wid] = ep; }
    __syncthreads();
    if (tid == 0) {
        cn = r[0][0] + r[0][1] + r[0][2] + r[0][3];
        sx = r[1][0] + r[1][1] + r[1][2] + r[1][3];
        sy = r[2][0] + r[2][1] + r[2][2] + r[2][3];
        ep = r[3][0] + r[3][1] + r[3][2] + r[3][3];
        float census = cn / (float)NPIX;
        float mx = sx / (float)((size_t)BB * 2 * HH * (WW - 1));
        float my = sy / (float)((size_t)BB * 2 * (HH - 1) * WW);
        out[0] = census + 0.5f * (mx + my);
        out[1] = ep / (float)NPIX;
    }
}

extern "C" void kernel_launch(void* const* d_in, const int* in_sizes, int n_in,
                              void* d_out, int out_size, void* d_ws, size_t ws_size,
                              hipStream_t stream) {
    const float* flow   = (const float*)d_in[0];
    const float* target = (const float*)d_in[1];
    const float* img1   = (const float*)d_in[2];
    const float* img2   = (const float*)d_in[3];
    float* out  = (float*)d_out;
    float* part = (float*)d_ws;   // 4*NB floats

    dim3 gr(NBX, NBY, BB);
    k_fused<<<gr, dim3(256, 1, 1), 0, stream>>>(flow, target, img1, img2, part);
    k_final<<<1, dim3(256, 1, 1), 0, stream>>>(part, out);
}